// Round 4
// baseline (88.513 us; speedup 1.0000x reference)
//
#include <hip/hip_runtime.h>

#define BATCH   32
#define SEQ     2048
#define MDIM    128
#define LBAS    64
#define NW      2041        // SEQ - RANK + 1
#define TW      16          // windows per tile
#define NTILE   8           // tiles per block -> 128 windows/block
#define NBLK    512         // 32 batches x 16 tile-groups
#define APAD    136         // bf16 elems per sA row

typedef __attribute__((ext_vector_type(8))) short  short8;
typedef __attribute__((ext_vector_type(4))) float  float4v;

__device__ __forceinline__ unsigned short f2bf(float f) {
    unsigned int u = __float_as_uint(f);
    return (unsigned short)((u + 0x7FFFu + ((u >> 16) & 1u)) >> 16);
}
__device__ __forceinline__ void store_bf16x4(unsigned short* p, float4v a) {
    unsigned int lo = (unsigned)f2bf(a.x) | ((unsigned)f2bf(a.y) << 16);
    unsigned int hi = (unsigned)f2bf(a.z) | ((unsigned)f2bf(a.w) << 16);
    *reinterpret_cast<unsigned long long*>(p) = ((unsigned long long)hi << 32) | lo;
}

// ---------------------------------------------------------------------------
// R11: single fused kernel, NO cooperative launch.
// R3 post-mortem: the fused numerics were bit-identical to the proven R0
// path (indices re-derived); the failure was cg::this_grid().sync() not
// synchronizing under the harness's graph capture (cooperative launch is
// not capture-safe) -> block 0 read stale partials. Fix: replace the final
// reduce with ONE device-scope atomicAdd(out, blocksum/8359936) per block.
// The harness hipMemsetAsync's out to 0 before every launch, and atomicAdd
// on global is device-scope by default on gfx950 -> correct across XCDs,
// capture-safe, and eliminates partial[]/workspace entirely.
// Body: R0-proven 512 blocks x 8 tiles, (256,2), 3-buffer raw staging,
// depth-2 global_load_lds prefetch, raw s_barrier + per-wave vmcnt(3).
// Prep inlined: raw M/Acoeff/Bbasis loads issued BEFORE the tile DMA (vmcnt
// retires in order, so the converts' implicit wait does not drain the DMA),
// then converted to bit-identical bfr/nkreg during DMA flight.
// ---------------------------------------------------------------------------
__global__ __launch_bounds__(256, 2)
void ndd_fused(const float* __restrict__ x,            // [32][2048][128]
               const float* __restrict__ Mmat,         // [128][128]
               const float* __restrict__ Acoeff,       // [128][64]
               const float* __restrict__ Bbasis,       // [64][128]
               float* __restrict__ out)                // [1], pre-zeroed
{
    __shared__ __align__(16) float sRaw[3][12 * 256];             // 3 x 12 KB
    __shared__ __align__(16) unsigned short sA[TW * APAD];        // 4.25 KB
    __shared__ float sred[4];

    const int tid  = threadIdx.x;
    const int lane = tid & 63;
    const int wave = tid >> 6;
    const int b    = blockIdx.x >> 4;          // batch
    const int base = (blockIdx.x & 15) * 128;  // window base (mult of 64)
    const float* xb = x + (size_t)b * SEQ * MDIM;

    const int l15 = lane & 15;
    const int q   = lane >> 4;
    const int nb  = wave * 32;                 // this wave's n-columns

    // ---- inlined-prep raw loads FIRST (older than DMA in vmcnt order) ----
    float4v mraw[4][2][2];                     // M rows for B-fragments
    #pragma unroll
    for (int kk = 0; kk < 4; ++kk)
        #pragma unroll
        for (int nj = 0; nj < 2; ++nj) {
            const float* src = Mmat + (size_t)(nb + nj * 16 + l15) * MDIM
                                    + (kk * 4 + q) * 8;
            mraw[kk][nj][0] = *reinterpret_cast<const float4v*>(src);
            mraw[kk][nj][1] = *reinterpret_cast<const float4v*>(src + 4);
        }
    float4v araw[4][2];
    float   braw[4][2][4];
    #pragma unroll
    for (int p = 0; p < 4; ++p)
        #pragma unroll
        for (int nj = 0; nj < 2; ++nj) {
            const int n  = nb + nj * 16 + l15;
            const int k0 = p * 16 + q * 4;
            araw[p][nj] = *reinterpret_cast<const float4v*>(
                Acoeff + (size_t)n * LBAS + k0);
            #pragma unroll
            for (int r = 0; r < 4; ++r)
                braw[p][nj][r] = Bbasis[(size_t)(k0 + r) * MDIM + n];
        }

    // ---- DMA: 12 chunks (24 rows) per tile, 3 chunks per wave ----
    auto issue = [&](int j) {
        const int W0r = base + j * TW;
        #pragma unroll
        for (int i = 0; i < 3; ++i) {
            const int c = wave * 3 + i;            // chunk 0..11
            int r0 = W0r + 2 * c;
            r0 = r0 > 2046 ? 2046 : r0;            // real rows only
            const float* g = xb + (size_t)r0 * MDIM + lane * 4;
            __builtin_amdgcn_global_load_lds(
                (const __attribute__((address_space(1))) void*)g,
                (__attribute__((address_space(3))) void*)&sRaw[j % 3][c * 256],
                16, 0, 0);
        }
    };
    __builtin_amdgcn_sched_barrier(0);
    issue(0);
    issue(1);
    __builtin_amdgcn_sched_barrier(0);

    // ---- converts: bit-identical bfr / nkreg vs the old prep kernel ----
    short8 bfr[4][2];
    #pragma unroll
    for (int kk = 0; kk < 4; ++kk)
        #pragma unroll
        for (int nj = 0; nj < 2; ++nj) {
            short8 v;
            #pragma unroll
            for (int j = 0; j < 8; ++j)
                v[j] = (short)f2bf(mraw[kk][nj][j >> 2][j & 3]);
            bfr[kk][nj] = v;
        }
    float4v nkreg[4][2];
    #pragma unroll
    for (int p = 0; p < 4; ++p)
        #pragma unroll
        for (int nj = 0; nj < 2; ++nj)
            #pragma unroll
            for (int r = 0; r < 4; ++r)
                nkreg[p][nj][r] = araw[p][nj][r] * braw[p][nj][r];

    float local = 0.f;

    #pragma unroll
    for (int j = 0; j < NTILE; ++j) {
        // wait: tile j's 3 chunks done (tile j+1's 3 may still fly)
        __builtin_amdgcn_sched_barrier(0);
        if (j == NTILE - 1) __builtin_amdgcn_s_waitcnt(0x0F70);  // vmcnt(0)
        else                __builtin_amdgcn_s_waitcnt(0x0F73);  // vmcnt(3)
        asm volatile("s_barrier" ::: "memory");
        __builtin_amdgcn_sched_barrier(0);

        // ---- phase 2: window means from raw[j%3] -> bf16 sA ----
        {
            const int m4 = tid & 31;
            const int wg = tid >> 5;               // windows wg*2, wg*2+1
            const float4v* R = reinterpret_cast<const float4v*>(&sRaw[j % 3][0]);
            float4v rows[9];
            #pragma unroll
            for (int i = 0; i < 9; ++i) rows[i] = R[(wg * 2 + i) * 32 + m4];
            float4v acc = ((rows[0] + rows[1]) + (rows[2] + rows[3])) +
                          ((rows[4] + rows[5]) + (rows[6] + rows[7]));
            store_bf16x4(&sA[(wg * 2) * APAD + m4 * 4], acc * 0.125f);
            acc += rows[8] - rows[0];
            store_bf16x4(&sA[(wg * 2 + 1) * APAD + m4 * 4], acc * 0.125f);
        }

        __builtin_amdgcn_sched_barrier(0);
        __builtin_amdgcn_s_waitcnt(0xC07F);        // lgkmcnt(0) only
        asm volatile("s_barrier" ::: "memory");
        __builtin_amdgcn_sched_barrier(0);

        // ---- depth-2 prefetch: tile j+2 into buffer (j+2)%3 ----
        if (j + 2 < NTILE) issue(j + 2);

        // ---- phase 3: MFMA C[w][n], pure LDS + registers ----
        float4v accf[2] = {(float4v){0.f,0.f,0.f,0.f}, (float4v){0.f,0.f,0.f,0.f}};
        #pragma unroll
        for (int kk = 0; kk < 4; ++kk) {
            const short8 af = *reinterpret_cast<const short8*>(
                &sA[l15 * APAD + kk * 32 + q * 8]);
            #pragma unroll
            for (int nj = 0; nj < 2; ++nj)
                accf[nj] = __builtin_amdgcn_mfma_f32_16x16x32_bf16(
                    af, bfr[kk][nj], accf[nj], 0, 0, 0);
        }

        // ---- epilogue: (C - nk)^2, masked ----
        const int p = j & 3;
        #pragma unroll
        for (int nj = 0; nj < 2; ++nj) {
            #pragma unroll
            for (int r = 0; r < 4; ++r) {
                const int w = base + j * TW + q * 4 + r;
                if (w < NW) {
                    const float d = accf[nj][r] - nkreg[p][nj][r];
                    local += d * d;
                }
            }
        }
    }

    // ---- block reduce -> one device-scope atomic into out ----
    #pragma unroll
    for (int off = 32; off > 0; off >>= 1)
        local += __shfl_down(local, off, 64);
    if (lane == 0) sred[wave] = local;
    __syncthreads();
    if (tid == 0)
        atomicAdd(out, ((sred[0] + sred[1]) + (sred[2] + sred[3]))
                       * (1.0f / 8359936.0f));
}

extern "C" void kernel_launch(void* const* d_in, const int* in_sizes, int n_in,
                              void* d_out, int out_size, void* d_ws, size_t ws_size,
                              hipStream_t stream) {
    const float* x     = (const float*)d_in[0];
    const float* Mmat  = (const float*)d_in[1];
    const float* Acoef = (const float*)d_in[2];
    const float* Bbas  = (const float*)d_in[3];
    float* out         = (float*)d_out;   // harness zeroes out before launch

    ndd_fused<<<NBLK, 256, 0, stream>>>(x, Mmat, Acoef, Bbas, out);
}

// Round 5
// 87.140 us; speedup vs baseline: 1.0158x; 1.0158x over previous
//
#include <hip/hip_runtime.h>

#define BATCH   32
#define SEQ     2048
#define MDIM    128
#define LBAS    64
#define NW      2041        // SEQ - RANK + 1
#define TW      16          // windows per tile
#define NTILE   8           // tiles per block -> 128 windows/block
#define NBLK    512         // 32 batches x 16 tile-groups
#define APAD    136         // bf16 elems per sA row

typedef __attribute__((ext_vector_type(8))) short  short8;
typedef __attribute__((ext_vector_type(4))) float  float4v;

__device__ __forceinline__ unsigned short f2bf(float f) {
    unsigned int u = __float_as_uint(f);
    return (unsigned short)((u + 0x7FFFu + ((u >> 16) & 1u)) >> 16);
}
__device__ __forceinline__ void store_bf16x4(unsigned short* p, float4v a) {
    unsigned int lo = (unsigned)f2bf(a.x) | ((unsigned)f2bf(a.y) << 16);
    unsigned int hi = (unsigned)f2bf(a.z) | ((unsigned)f2bf(a.w) << 16);
    *reinterpret_cast<unsigned long long*>(p) = ((unsigned long long)hi << 32) | lo;
}

// ---------------------------------------------------------------------------
// Prep: M -> bf16 B-fragment-linear Mb[(k>>3)*128+n][j];
//       nkT[n][k] = Acoeff[n][k] * Bbasis[k][n]   (TRANSPOSED: main loads f4)
// R4 lesson: per-block inlined prep costs ~+10us (56 VMEM incl. strided
// Bbasis gather + converts on every block's critical path). Keep this as a
// separate tiny kernel; main reads the converted 64 KB back from L2.
// ---------------------------------------------------------------------------
__global__ __launch_bounds__(256)
void ndd_prep(const float* __restrict__ Mmat,
              const float* __restrict__ Acoeff,
              const float* __restrict__ Bbasis,
              unsigned short* __restrict__ Mb,
              float* __restrict__ nkT)
{
    const int gid = blockIdx.x * 256 + threadIdx.x;
    if (gid < 2048) {                    // 128 rows x 16 k-chunks
        const int n = gid >> 4;
        const int c = gid & 15;
        const float* src = Mmat + n * MDIM + c * 8;
        short8 v;
        #pragma unroll
        for (int j = 0; j < 8; ++j) v[j] = (short)f2bf(src[j]);
        *reinterpret_cast<short8*>(Mb + ((size_t)(c * MDIM + n)) * 8) = v;
    } else if (gid < 2048 + 8192) {      // nkT: [128][64]
        const int e = gid - 2048;
        const int n = e >> 6;
        const int k = e & 63;
        nkT[e] = Acoeff[e] * Bbasis[k * MDIM + n];   // Acoeff is [n][k] too
    }
}

// ---------------------------------------------------------------------------
// Main (R12): R0-proven body BYTE-IDENTICAL (512 blocks x 8 tiles, (256,2),
// 3-buffer raw staging, depth-2 global_load_lds prefetch, raw s_barrier +
// per-wave vmcnt(3)), with ONE delta: the final block reduce ends in a
// device-scope atomicAdd(out, blocksum/8359936) -- validated correct in R4
// (harness hipMemsetAsync zeroes out before each launch; global atomicAdd
// is device-scope on gfx950, XCD-safe, graph-capture-safe). This deletes
// the ndd_reduce dispatch and its graph gap.
// Failed-lever ledger: R1 de-persist (90.5), R2 (256,3) occupancy (86.3),
// R3 cooperative grid.sync (broken under capture), R4 inlined prep (88.5).
// ---------------------------------------------------------------------------
__global__ __launch_bounds__(256, 2)
void ndd_main(const float* __restrict__ x,            // [32][2048][128]
              const unsigned short* __restrict__ Mb,  // bf16 frag-linear
              const float* __restrict__ nkT,          // [128][64]
              float* __restrict__ out)                // [1], pre-zeroed
{
    __shared__ __align__(16) float sRaw[3][12 * 256];             // 3 x 12 KB
    __shared__ __align__(16) unsigned short sA[TW * APAD];        // 4.25 KB
    __shared__ float sred[4];

    const int tid  = threadIdx.x;
    const int lane = tid & 63;
    const int wave = tid >> 6;
    const int b    = blockIdx.x >> 4;          // batch
    const int base = (blockIdx.x & 15) * 128;  // window base (mult of 64)
    const float* xb = x + (size_t)b * SEQ * MDIM;

    const int l15 = lane & 15;
    const int q   = lane >> 4;
    const int nb  = wave * 32;                 // this wave's n-columns

    // ---- hoist B-fragments (tile-invariant): 8 frags = 32 VGPRs ----
    short8 bfr[4][2];
    #pragma unroll
    for (int kk = 0; kk < 4; ++kk)
        #pragma unroll
        for (int nj = 0; nj < 2; ++nj)
            bfr[kk][nj] = *reinterpret_cast<const short8*>(
                Mb + ((size_t)((kk * 4 + q) * MDIM + nb + nj * 16 + l15)) * 8);

    // ---- hoist nk via nkT: k = p*16 + q*4 + r -> one float4 per (p,nj) ----
    float4v nkreg[4][2];
    #pragma unroll
    for (int p = 0; p < 4; ++p)
        #pragma unroll
        for (int nj = 0; nj < 2; ++nj)
            nkreg[p][nj] = *reinterpret_cast<const float4v*>(
                nkT + (size_t)(nb + nj * 16 + l15) * LBAS + p * 16 + q * 4);

    // ---- DMA: 12 chunks (24 rows) per tile, 3 chunks per wave ----
    auto issue = [&](int j) {
        const int W0r = base + j * TW;
        #pragma unroll
        for (int i = 0; i < 3; ++i) {
            const int c = wave * 3 + i;            // chunk 0..11
            int r0 = W0r + 2 * c;
            r0 = r0 > 2046 ? 2046 : r0;            // real rows only
            const float* g = xb + (size_t)r0 * MDIM + lane * 4;
            __builtin_amdgcn_global_load_lds(
                (const __attribute__((address_space(1))) void*)g,
                (__attribute__((address_space(3))) void*)&sRaw[j % 3][c * 256],
                16, 0, 0);
        }
    };
    issue(0);
    issue(1);

    float local = 0.f;

    #pragma unroll
    for (int j = 0; j < NTILE; ++j) {
        // wait: tile j's 3 chunks done (tile j+1's 3 may still fly)
        __builtin_amdgcn_sched_barrier(0);
        if (j == NTILE - 1) __builtin_amdgcn_s_waitcnt(0x0F70);  // vmcnt(0)
        else                __builtin_amdgcn_s_waitcnt(0x0F73);  // vmcnt(3)
        asm volatile("s_barrier" ::: "memory");
        __builtin_amdgcn_sched_barrier(0);

        // ---- phase 2: window means from raw[j%3] -> bf16 sA ----
        {
            const int m4 = tid & 31;
            const int wg = tid >> 5;               // windows wg*2, wg*2+1
            const float4v* R = reinterpret_cast<const float4v*>(&sRaw[j % 3][0]);
            float4v rows[9];
            #pragma unroll
            for (int i = 0; i < 9; ++i) rows[i] = R[(wg * 2 + i) * 32 + m4];
            float4v acc = ((rows[0] + rows[1]) + (rows[2] + rows[3])) +
                          ((rows[4] + rows[5]) + (rows[6] + rows[7]));
            store_bf16x4(&sA[(wg * 2) * APAD + m4 * 4], acc * 0.125f);
            acc += rows[8] - rows[0];
            store_bf16x4(&sA[(wg * 2 + 1) * APAD + m4 * 4], acc * 0.125f);
        }

        __builtin_amdgcn_sched_barrier(0);
        __builtin_amdgcn_s_waitcnt(0xC07F);        // lgkmcnt(0) only
        asm volatile("s_barrier" ::: "memory");
        __builtin_amdgcn_sched_barrier(0);

        // ---- depth-2 prefetch: tile j+2 into buffer (j+2)%3 ----
        if (j + 2 < NTILE) issue(j + 2);

        // ---- phase 3: MFMA C[w][n], pure LDS + registers ----
        float4v accf[2] = {(float4v){0.f,0.f,0.f,0.f}, (float4v){0.f,0.f,0.f,0.f}};
        #pragma unroll
        for (int kk = 0; kk < 4; ++kk) {
            const short8 af = *reinterpret_cast<const short8*>(
                &sA[l15 * APAD + kk * 32 + q * 8]);
            #pragma unroll
            for (int nj = 0; nj < 2; ++nj)
                accf[nj] = __builtin_amdgcn_mfma_f32_16x16x32_bf16(
                    af, bfr[kk][nj], accf[nj], 0, 0, 0);
        }

        // ---- epilogue: (C - nk)^2, masked ----
        const int p = j & 3;
        #pragma unroll
        for (int nj = 0; nj < 2; ++nj) {
            #pragma unroll
            for (int r = 0; r < 4; ++r) {
                const int w = base + j * TW + q * 4 + r;
                if (w < NW) {
                    const float d = accf[nj][r] - nkreg[p][nj][r];
                    local += d * d;
                }
            }
        }
    }

    // ---- block reduce -> one device-scope atomic into out ----
    #pragma unroll
    for (int off = 32; off > 0; off >>= 1)
        local += __shfl_down(local, off, 64);
    if (lane == 0) sred[wave] = local;
    __syncthreads();
    if (tid == 0)
        atomicAdd(out, ((sred[0] + sred[1]) + (sred[2] + sred[3]))
                       * (1.0f / 8359936.0f));
}

extern "C" void kernel_launch(void* const* d_in, const int* in_sizes, int n_in,
                              void* d_out, int out_size, void* d_ws, size_t ws_size,
                              hipStream_t stream) {
    const float* x     = (const float*)d_in[0];
    const float* Mmat  = (const float*)d_in[1];
    const float* Acoef = (const float*)d_in[2];
    const float* Bbas  = (const float*)d_in[3];
    float* out         = (float*)d_out;   // harness zeroes out before launch

    unsigned short* Mb = (unsigned short*)d_ws;             // 32 KB bf16
    float* nkTp        = (float*)((char*)d_ws + 32768);     // 32 KB fp32

    ndd_prep<<<40, 256, 0, stream>>>(Mmat, Acoef, Bbas, Mb, nkTp);
    ndd_main<<<NBLK, 256, 0, stream>>>(x, Mb, nkTp, out);
}

// Round 6
// 85.539 us; speedup vs baseline: 1.0348x; 1.0187x over previous
//
#include <hip/hip_runtime.h>

#define BATCH   32
#define SEQ     2048
#define MDIM    128
#define LBAS    64
#define NW      2041        // SEQ - RANK + 1
#define TW      16          // windows per tile
#define NTILE   8           // tiles per block -> 128 windows/block
#define APAD    136         // bf16 elems per sA row

typedef __attribute__((ext_vector_type(8))) short  short8;
typedef __attribute__((ext_vector_type(4))) float  float4v;

__device__ __forceinline__ unsigned short f2bf(float f) {
    unsigned int u = __float_as_uint(f);
    return (unsigned short)((u + 0x7FFFu + ((u >> 16) & 1u)) >> 16);
}
__device__ __forceinline__ void store_bf16x4(unsigned short* p, float4v a) {
    unsigned int lo = (unsigned)f2bf(a.x) | ((unsigned)f2bf(a.y) << 16);
    unsigned int hi = (unsigned)f2bf(a.z) | ((unsigned)f2bf(a.w) << 16);
    *reinterpret_cast<unsigned long long*>(p) = ((unsigned long long)hi << 32) | lo;
}

// ---------------------------------------------------------------------------
// R13: EXACT revert to the all-time-best R0 artifact (82.8 us) as a
// discriminating experiment. R5 (R0 body + atomicAdd reduce, -1 dispatch)
// was 87.1 -- SLOWER than R0 despite doing strictly less dispatch work.
// Hypothesis A (atomic tail): 512 same-address fp32 atomicAdds serialize at
// the coherence point; ~256 blocks retire together -> ~5-8 us tail. In-
// session ranking supports it (atomic variants 87.1/88.5 vs store+reduce
// 86.3). Hypothesis B: +-4 us session noise (fill varied 42.4-46.6).
// This byte-identical R0 re-run discriminates: ~82-84 -> A (keep this base,
// atomics are banned); ~86-88 -> B (kernel deltas below noise; declare
// harness-dominated roofline next round).
// Failed-lever ledger: R1 de-persist (90.5), R2 (256,3)+1024blk (86.3),
// R3 coop grid.sync (broken under capture), R4 inlined prep (88.5),
// R5 same-address atomicAdd epilogue (87.1).
// ---------------------------------------------------------------------------
__global__ __launch_bounds__(256)
void ndd_prep(const float* __restrict__ Mmat,
              const float* __restrict__ Acoeff,
              const float* __restrict__ Bbasis,
              unsigned short* __restrict__ Mb,
              float* __restrict__ nkT)
{
    const int gid = blockIdx.x * 256 + threadIdx.x;
    if (gid < 2048) {                    // 128 rows x 16 k-chunks
        const int n = gid >> 4;
        const int c = gid & 15;
        const float* src = Mmat + n * MDIM + c * 8;
        short8 v;
        #pragma unroll
        for (int j = 0; j < 8; ++j) v[j] = (short)f2bf(src[j]);
        *reinterpret_cast<short8*>(Mb + ((size_t)(c * MDIM + n)) * 8) = v;
    } else if (gid < 2048 + 8192) {      // nkT: [128][64]
        const int e = gid - 2048;
        const int n = e >> 6;
        const int k = e & 63;
        nkT[e] = Acoeff[e] * Bbasis[k * MDIM + n];   // Acoeff is [n][k] too
    }
}

__global__ __launch_bounds__(256, 2)
void ndd_main(const float* __restrict__ x,            // [32][2048][128]
              const unsigned short* __restrict__ Mb,  // bf16 frag-linear
              const float* __restrict__ nkT,          // [128][64]
              float* __restrict__ partial)            // [512]
{
    __shared__ __align__(16) float sRaw[3][12 * 256];             // 3 x 12 KB
    __shared__ __align__(16) unsigned short sA[TW * APAD];        // 4.25 KB
    __shared__ float sred[4];

    const int tid  = threadIdx.x;
    const int lane = tid & 63;
    const int wave = tid >> 6;
    const int b    = blockIdx.x >> 4;          // batch
    const int base = (blockIdx.x & 15) * 128;  // window base (mult of 64)
    const float* xb = x + (size_t)b * SEQ * MDIM;

    const int l15 = lane & 15;
    const int q   = lane >> 4;
    const int nb  = wave * 32;                 // this wave's n-columns

    // ---- hoist B-fragments (tile-invariant): 8 frags = 32 VGPRs ----
    short8 bfr[4][2];
    #pragma unroll
    for (int kk = 0; kk < 4; ++kk)
        #pragma unroll
        for (int nj = 0; nj < 2; ++nj)
            bfr[kk][nj] = *reinterpret_cast<const short8*>(
                Mb + ((size_t)((kk * 4 + q) * MDIM + nb + nj * 16 + l15)) * 8);

    // ---- hoist nk via nkT: k = p*16 + q*4 + r -> one float4 per (p,nj) ----
    float4v nkreg[4][2];
    #pragma unroll
    for (int p = 0; p < 4; ++p)
        #pragma unroll
        for (int nj = 0; nj < 2; ++nj)
            nkreg[p][nj] = *reinterpret_cast<const float4v*>(
                nkT + (size_t)(nb + nj * 16 + l15) * LBAS + p * 16 + q * 4);

    // ---- DMA: 12 chunks (24 rows) per tile, 3 chunks per wave ----
    auto issue = [&](int j) {
        const int W0r = base + j * TW;
        #pragma unroll
        for (int i = 0; i < 3; ++i) {
            const int c = wave * 3 + i;            // chunk 0..11
            int r0 = W0r + 2 * c;
            r0 = r0 > 2046 ? 2046 : r0;            // real rows only
            const float* g = xb + (size_t)r0 * MDIM + lane * 4;
            __builtin_amdgcn_global_load_lds(
                (const __attribute__((address_space(1))) void*)g,
                (__attribute__((address_space(3))) void*)&sRaw[j % 3][c * 256],
                16, 0, 0);
        }
    };
    issue(0);
    issue(1);

    float local = 0.f;

    #pragma unroll
    for (int j = 0; j < NTILE; ++j) {
        // wait: tile j's 3 chunks done (tile j+1's 3 may still fly)
        __builtin_amdgcn_sched_barrier(0);
        if (j == NTILE - 1) __builtin_amdgcn_s_waitcnt(0x0F70);  // vmcnt(0)
        else                __builtin_amdgcn_s_waitcnt(0x0F73);  // vmcnt(3)
        asm volatile("s_barrier" ::: "memory");
        __builtin_amdgcn_sched_barrier(0);

        // ---- phase 2: window means from raw[j%3] -> bf16 sA ----
        {
            const int m4 = tid & 31;
            const int wg = tid >> 5;               // windows wg*2, wg*2+1
            const float4v* R = reinterpret_cast<const float4v*>(&sRaw[j % 3][0]);
            float4v rows[9];
            #pragma unroll
            for (int i = 0; i < 9; ++i) rows[i] = R[(wg * 2 + i) * 32 + m4];
            float4v acc = ((rows[0] + rows[1]) + (rows[2] + rows[3])) +
                          ((rows[4] + rows[5]) + (rows[6] + rows[7]));
            store_bf16x4(&sA[(wg * 2) * APAD + m4 * 4], acc * 0.125f);
            acc += rows[8] - rows[0];
            store_bf16x4(&sA[(wg * 2 + 1) * APAD + m4 * 4], acc * 0.125f);
        }

        __builtin_amdgcn_sched_barrier(0);
        __builtin_amdgcn_s_waitcnt(0xC07F);        // lgkmcnt(0) only
        asm volatile("s_barrier" ::: "memory");
        __builtin_amdgcn_sched_barrier(0);

        // ---- depth-2 prefetch: tile j+2 into buffer (j+2)%3 ----
        if (j + 2 < NTILE) issue(j + 2);

        // ---- phase 3: MFMA C[w][n], pure LDS + registers ----
        float4v accf[2] = {(float4v){0.f,0.f,0.f,0.f}, (float4v){0.f,0.f,0.f,0.f}};
        #pragma unroll
        for (int kk = 0; kk < 4; ++kk) {
            const short8 af = *reinterpret_cast<const short8*>(
                &sA[l15 * APAD + kk * 32 + q * 8]);
            #pragma unroll
            for (int nj = 0; nj < 2; ++nj)
                accf[nj] = __builtin_amdgcn_mfma_f32_16x16x32_bf16(
                    af, bfr[kk][nj], accf[nj], 0, 0, 0);
        }

        // ---- epilogue: (C - nk)^2, masked ----
        const int p = j & 3;
        #pragma unroll
        for (int nj = 0; nj < 2; ++nj) {
            #pragma unroll
            for (int r = 0; r < 4; ++r) {
                const int w = base + j * TW + q * 4 + r;
                if (w < NW) {
                    const float d = accf[nj][r] - nkreg[p][nj][r];
                    local += d * d;
                }
            }
        }
    }

    // ---- block reduce -> one partial ----
    #pragma unroll
    for (int off = 32; off > 0; off >>= 1)
        local += __shfl_down(local, off, 64);
    if (lane == 0) sred[wave] = local;
    __syncthreads();
    if (tid == 0)
        partial[blockIdx.x] = (sred[0] + sred[1]) + (sred[2] + sred[3]);
}

// ---------------------------------------------------------------------------
// Final reduce: 512 partials -> scalar D
// ---------------------------------------------------------------------------
__global__ __launch_bounds__(256)
void ndd_reduce(const float* __restrict__ partial, float* __restrict__ out)
{
    __shared__ float sred[4];
    float s = partial[threadIdx.x] + partial[threadIdx.x + 256];
    #pragma unroll
    for (int off = 32; off > 0; off >>= 1) s += __shfl_down(s, off, 64);
    if ((threadIdx.x & 63) == 0) sred[threadIdx.x >> 6] = s;
    __syncthreads();
    if (threadIdx.x == 0)
        out[0] = ((sred[0] + sred[1]) + (sred[2] + sred[3])) * (1.0f / 8359936.0f);
}

extern "C" void kernel_launch(void* const* d_in, const int* in_sizes, int n_in,
                              void* d_out, int out_size, void* d_ws, size_t ws_size,
                              hipStream_t stream) {
    const float* x     = (const float*)d_in[0];
    const float* Mmat  = (const float*)d_in[1];
    const float* Acoef = (const float*)d_in[2];
    const float* Bbas  = (const float*)d_in[3];
    float* out         = (float*)d_out;

    unsigned short* Mb = (unsigned short*)d_ws;             // 32 KB bf16
    float* nkTp        = (float*)((char*)d_ws + 32768);     // 32 KB fp32
    float* part        = (float*)((char*)d_ws + 65536);     // 2 KB partials

    ndd_prep<<<40, 256, 0, stream>>>(Mmat, Acoef, Bbas, Mb, nkTp);
    ndd_main<<<512, 256, 0, stream>>>(x, Mb, nkTp, part);
    ndd_reduce<<<1, 256, 0, stream>>>(part, out);
}

// Round 8
// 83.961 us; speedup vs baseline: 1.0542x; 1.0188x over previous
//
#include <hip/hip_runtime.h>

#define BATCH   32
#define SEQ     2048
#define MDIM    128
#define LBAS    64
#define NW      2041        // SEQ - RANK + 1
#define APAD    136         // bf16 elems per sA row
#define NBLK    512         // 32 batches x 16 groups of 128 windows

typedef __attribute__((ext_vector_type(8))) short  short8;
typedef __attribute__((ext_vector_type(4))) float  float4v;
typedef __attribute__((ext_vector_type(2))) float  float2v;

__device__ __forceinline__ unsigned short f2bf(float f) {
    unsigned int u = __float_as_uint(f);
    return (unsigned short)((u + 0x7FFFu + ((u >> 16) & 1u)) >> 16);
}

// ---------------------------------------------------------------------------
// Prep: M -> bf16 B-fragment-linear Mb[(k>>3)*128+n][j];
//       nkT[n][k] = Acoeff[n][k] * Bbasis[k][n]   (TRANSPOSED: main loads f4)
// ---------------------------------------------------------------------------
__global__ __launch_bounds__(256)
void ndd_prep(const float* __restrict__ Mmat,
              const float* __restrict__ Acoeff,
              const float* __restrict__ Bbasis,
              unsigned short* __restrict__ Mb,
              float* __restrict__ nkT)
{
    const int gid = blockIdx.x * 256 + threadIdx.x;
    if (gid < 2048) {                    // 128 rows x 16 k-chunks
        const int n = gid >> 4;
        const int c = gid & 15;
        const float* src = Mmat + n * MDIM + c * 8;
        short8 v;
        #pragma unroll
        for (int j = 0; j < 8; ++j) v[j] = (short)f2bf(src[j]);
        *reinterpret_cast<short8*>(Mb + ((size_t)(c * MDIM + n)) * 8) = v;
    } else if (gid < 2048 + 8192) {      // nkT: [128][64]
        const int e = gid - 2048;
        const int n = e >> 6;
        const int k = e & 63;
        nkT[e] = Acoeff[e] * Bbasis[k * MDIM + n];   // Acoeff is [n][k] too
    }
}

// ---------------------------------------------------------------------------
// Main (R15 = R14 resubmit; R7 bench was an infra failure, kernel unmeasured).
// R6 established: noise +-3us; R0-main ~30-33us vs ~7us HBM floor, i.e.
// ~20us of stall inside the 16-barrier tile loop (vmcnt-wait -> barrier ->
// LDS mean -> barrier -> MFMA per tile, DMA lead ~= latency, marginal).
// This kernel DELETES that structure instead of tuning it:
//  - wave v owns 32 consecutive windows; loads its 39 rows coalesced into
//    REGISTERS (39 x float2/thread, all in flight; compiler emits staged
//    vmcnt waits -- 39-deep per-thread pipeline, no barriers involved);
//  - window means via register sliding sum  s += row[w+7] - row[w-1]
//    (same reassociation trick the proven kernel used for odd windows;
//    drift ~1e-5 on agg, 100x below agg's bf16 quantization);
//  - bf16 pack straight to sA; ONE __syncthreads; then the proven MFMA +
//    epilogue phase verbatim over 8 window-groups of 16.
// Fetch 96->80 KB/block (48->41 MB). LDS 34.4 KB, ~160-190 VGPR -> 2 blk/CU.
// Failed-lever ledger: R1 de-persist (90.5), R2 (256,3)+1024blk (86.3),
// R3 coop grid.sync (broken), R4 inlined prep (88.5), R5 same-address
// atomicAdd (87.1), R6 identical-R0 re-run (85.5 -> noise +-3us),
// R7 infra failure (no data).
// ---------------------------------------------------------------------------
__global__ __launch_bounds__(256, 2)
void ndd_main(const float* __restrict__ x,            // [32][2048][128]
              const unsigned short* __restrict__ Mb,  // bf16 frag-linear
              const float* __restrict__ nkT,          // [128][64]
              float* __restrict__ partial)            // [512]
{
    __shared__ __align__(16) unsigned short sA[128 * APAD];   // 34 KB
    __shared__ float sred[4];

    const int tid  = threadIdx.x;
    const int lane = tid & 63;
    const int wave = tid >> 6;
    const int b    = blockIdx.x >> 4;          // batch
    const int base = (blockIdx.x & 15) * 128;  // window base (mult of 128)
    const float* xb = x + (size_t)b * SEQ * MDIM;

    // ---- 39 coalesced row loads -> registers (critical path: issue first) ----
    // wave v covers windows [base+32v, base+32v+31] -> rows base+32v..+38.
    const int r0 = base + wave * 32;
    float2v rows[39];
    #pragma unroll
    for (int k = 0; k < 39; ++k) {
        int rr = r0 + k;
        rr = rr > 2047 ? 2047 : rr;            // tail clamp (masked later)
        rows[k] = *reinterpret_cast<const float2v*>(
            xb + (size_t)rr * MDIM + lane * 2);
    }

    // ---- hoists (issued after rows; consumed only after the barrier) ----
    const int l15 = lane & 15;
    const int q   = lane >> 4;
    const int nb  = wave * 32;                 // this wave's n-columns
    short8 bfr[4][2];
    #pragma unroll
    for (int kk = 0; kk < 4; ++kk)
        #pragma unroll
        for (int nj = 0; nj < 2; ++nj)
            bfr[kk][nj] = *reinterpret_cast<const short8*>(
                Mb + ((size_t)((kk * 4 + q) * MDIM + nb + nj * 16 + l15)) * 8);
    float4v nkreg[4][2];
    #pragma unroll
    for (int p = 0; p < 4; ++p)
        #pragma unroll
        for (int nj = 0; nj < 2; ++nj)
            nkreg[p][nj] = *reinterpret_cast<const float4v*>(
                nkT + (size_t)(nb + nj * 16 + l15) * LBAS + p * 16 + q * 4);

    // ---- sliding-window means -> bf16 sA (thread owns cols 2*lane..+1) ----
    unsigned short* myA = sA + (size_t)(wave * 32) * APAD + lane * 2;
    float2v s = ((rows[0] + rows[1]) + (rows[2] + rows[3])) +
                ((rows[4] + rows[5]) + (rows[6] + rows[7]));
    {
        float2v m = s * 0.125f;
        *reinterpret_cast<unsigned int*>(myA) =
            (unsigned)f2bf(m.x) | ((unsigned)f2bf(m.y) << 16);
    }
    #pragma unroll
    for (int w = 1; w < 32; ++w) {
        s += rows[w + 7] - rows[w - 1];
        float2v m = s * 0.125f;
        *reinterpret_cast<unsigned int*>(myA + (size_t)w * APAD) =
            (unsigned)f2bf(m.x) | ((unsigned)f2bf(m.y) << 16);
    }

    __syncthreads();                           // the ONLY main-phase barrier

    // ---- MFMA + epilogue: proven phase-3 verbatim, 8 window-groups ----
    float local = 0.f;
    #pragma unroll
    for (int wg = 0; wg < 8; ++wg) {
        float4v accf[2] = {(float4v){0.f,0.f,0.f,0.f}, (float4v){0.f,0.f,0.f,0.f}};
        #pragma unroll
        for (int kk = 0; kk < 4; ++kk) {
            const short8 af = *reinterpret_cast<const short8*>(
                &sA[(wg * 16 + l15) * APAD + kk * 32 + q * 8]);
            #pragma unroll
            for (int nj = 0; nj < 2; ++nj)
                accf[nj] = __builtin_amdgcn_mfma_f32_16x16x32_bf16(
                    af, bfr[kk][nj], accf[nj], 0, 0, 0);
        }
        const int p = wg & 3;                  // kmod = (wg%4)*16 + q*4 + r
        #pragma unroll
        for (int nj = 0; nj < 2; ++nj) {
            #pragma unroll
            for (int r = 0; r < 4; ++r) {
                const int w = base + wg * 16 + q * 4 + r;
                if (w < NW) {
                    const float d = accf[nj][r] - nkreg[p][nj][r];
                    local += d * d;
                }
            }
        }
    }

    // ---- block reduce -> one partial (atomics banned per R5/R6) ----
    #pragma unroll
    for (int off = 32; off > 0; off >>= 1)
        local += __shfl_down(local, off, 64);
    if (lane == 0) sred[wave] = local;
    __syncthreads();
    if (tid == 0)
        partial[blockIdx.x] = (sred[0] + sred[1]) + (sred[2] + sred[3]);
}

// ---------------------------------------------------------------------------
// Final reduce: 512 partials -> scalar D
// ---------------------------------------------------------------------------
__global__ __launch_bounds__(256)
void ndd_reduce(const float* __restrict__ partial, float* __restrict__ out)
{
    __shared__ float sred[4];
    float s = partial[threadIdx.x] + partial[threadIdx.x + 256];
    #pragma unroll
    for (int off = 32; off > 0; off >>= 1) s += __shfl_down(s, off, 64);
    if ((threadIdx.x & 63) == 0) sred[threadIdx.x >> 6] = s;
    __syncthreads();
    if (threadIdx.x == 0)
        out[0] = ((sred[0] + sred[1]) + (sred[2] + sred[3])) * (1.0f / 8359936.0f);
}

extern "C" void kernel_launch(void* const* d_in, const int* in_sizes, int n_in,
                              void* d_out, int out_size, void* d_ws, size_t ws_size,
                              hipStream_t stream) {
    const float* x     = (const float*)d_in[0];
    const float* Mmat  = (const float*)d_in[1];
    const float* Acoef = (const float*)d_in[2];
    const float* Bbas  = (const float*)d_in[3];
    float* out         = (float*)d_out;

    unsigned short* Mb = (unsigned short*)d_ws;             // 32 KB bf16
    float* nkTp        = (float*)((char*)d_ws + 32768);     // 32 KB fp32
    float* part        = (float*)((char*)d_ws + 65536);     // 2 KB partials

    ndd_prep<<<40, 256, 0, stream>>>(Mmat, Acoef, Bbas, Mb, nkTp);
    ndd_main<<<NBLK, 256, 0, stream>>>(x, Mb, nkTp, part);
    ndd_reduce<<<1, 256, 0, stream>>>(part, out);
}